// Round 8
// baseline (259.830 us; speedup 1.0000x reference)
//
#include <hip/hip_runtime.h>
#include <math.h>

// SSIM-with-logits fused kernel for MI355X (gfx950). Round 12.
// R11 post-mortem: forcing v_pk_*_f32 left VALU busy-time unchanged
// (~50us) -> packed f32 is HALF-RATE on CDNA4 (fp32 peak is already
// reached by scalar v_fma_f32; VOP3P f32 = 2 SIMD passes). Scored bench
// unchanged (182 = 89us dispatch + ~93us fixed harness overhead).
// The kernel is VALU-CYCLE-bound: the lever is fewer scalar ops.
// R12: 4-channel staging. The four filtered fields are linear in
// (a, b, s=a^2+b^2, p=a*b). Compute s,p ONCE per staged pixel (+3
// instr/row) instead of per-tap products: horizontal drops 77->44
// instr/row (4 independent fma chains), vertical unchanged 44.
// Core ~125 -> ~91 instr/row (-27%).
//  - LDS: float4[11][76] per wave, SINGLE buffer (within-wave DS
//    in-order makes double-buffering redundant) -> stays 53.5 KB
//  - ds_read_b64 -> b128 (LDS pipe ~132 cyc/row, still < VALU)
//  - EDGE-templated pipeline: 6/8 interior bands skip reflect_i
//  - plain f2/scalar code restored (no inline asm)
//  - __launch_bounds__(256,2): the only spill-free bound (R3/R5/R6)

typedef __attribute__((ext_vector_type(4))) float f4;

#define H_IMG 1024
#define W_IMG 1024
#define N_IMG 16
#define WAVE_W 64        // output columns per wave
#define TILE_H 128       // output rows per wave
#define PADR 5
#define LDS_S4 76        // f4 cells per staged row (64 + 10 halo + pad)

// Normalized 1D Gaussian, WS=11, sigma=1.5 (absmax 0.0 in R1-R11)
constexpr float GW[11] = {
    0.00102838f, 0.00759877f, 0.03600077f, 0.10936069f, 0.21300553f,
    0.26601172f,
    0.21300553f, 0.10936069f, 0.03600077f, 0.00759877f, 0.00102838f};

__device__ __forceinline__ int reflect_i(int i, int n) {
    i = (i < 0) ? -i : i;
    i = (i >= n) ? (2 * n - 2 - i) : i;
    return i;
}

__device__ __forceinline__ float fast_sigmoid(float x) {
    return __builtin_amdgcn_rcpf(1.0f + __expf(-x));
}

// mu1,mu2 = filtered means; ss = F(a^2+b^2); pp = F(ab)
__device__ __forceinline__ void ssim_emit(
    float mu1, float mu2, float ss, float pp, float& loss_sum)
{
    const float mu1s = mu1 * mu1;
    const float mu2s = mu2 * mu2;
    const float mu12 = mu1 * mu2;
    const float ssum = ss - mu1s - mu2s;   // sigma1^2 + sigma2^2
    const float s12  = pp - mu12;
    const float C1 = 1e-4f, C2 = 9e-4f;
    const float num = (2.0f * mu12 + C1) * (2.0f * s12 + C2);
    const float den = (mu1s + mu2s + C1) * (ssum + C2);
    float l = 1.0f - num * __builtin_amdgcn_rcpf(den);
    l = fminf(fmaxf(l, 0.0f), 1.0f) * 0.5f;
    loss_sum += l;
}

// Issue global loads for NR rows of group at base gb into prefetch regs.
// EDGE=false (interior bands): row index is always in range, no reflect.
template<int NR, bool EDGE>
__device__ __forceinline__ void load_group(
    const float* __restrict__ A, const float* __restrict__ B,
    int y_start, int gb, int c0, int c1, int lane,
    float (&pa)[11], float (&pb)[11], float (&pa2)[11], float (&pb2)[11])
{
#pragma unroll
    for (int r = 0; r < NR; ++r) {
        const int yr = y_start + gb + r;
        const int yy = EDGE ? reflect_i(yr, H_IMG) : yr;
        const size_t ro = (size_t)yy << 10;   // *W_IMG
        pa[r] = A[ro + c0];
        pb[r] = B[ro + c0];
        if (lane < 2 * PADR) {
            pa2[r] = A[ro + c1];
            pb2[r] = B[ro + c1];
        }
    }
}

// Sigmoid + channel precompute + write NR rows into this wave's buffer.
// Channels: x=a=sigmoid(in), y=b, z=a^2+b^2, w=a*b.
template<int NR>
__device__ __forceinline__ void write_group(
    f4 (*__restrict__ buf)[LDS_S4], int lane,
    const float (&pa)[11], const float (&pb)[11],
    const float (&pa2)[11], const float (&pb2)[11])
{
#pragma unroll
    for (int r = 0; r < NR; ++r) {
        {
            const float a = fast_sigmoid(pa[r]);
            const float b = pb[r];
            buf[r][lane] = (f4){a, b, fmaf(a, a, b * b), a * b};
        }
        if (lane < 2 * PADR) {
            const float a = fast_sigmoid(pa2[r]);
            const float b = pb2[r];
            buf[r][WAVE_W + lane] = (f4){a, b, fmaf(a, a, b * b), a * b};
        }
    }
}

// Process NR staged rows. Group base == 0 mod 11 so mod-11 slot indices
// fold to compile-time constants (validated R2-R11). GUARD: first group
// (edge); invalid taps skipped, only r==10 completes an output.
// No barrier, no double buffer: DS ops are in-order within a wave, so
// this group's ds_reads complete before the next group's ds_writes.
template<int NR, bool GUARD>
__device__ __forceinline__ void process_group(
    const f4 (*__restrict__ buf)[LDS_S4], int lane,
    float (&va)[11], float (&vb)[11], float (&vs_)[11], float (&vp)[11],
    float& loss_sum)
{
#pragma unroll
    for (int r = 0; r < NR; ++r) {
        // ---- horizontal 11-tap: 4 fma/tap, 4 independent chains ----
        float hA = 0.0f, hB = 0.0f, hS = 0.0f, hP = 0.0f;
#pragma unroll
        for (int k = 0; k < 11; ++k) {
            const f4 v = buf[r][lane + k];
            hA = fmaf(GW[k], v.x, hA);
            hB = fmaf(GW[k], v.y, hB);
            hS = fmaf(GW[k], v.z, hS);
            hP = fmaf(GW[k], v.w, hP);
        }
        // ---- vertical scatter into mod-11 slots: 4 fma/slot ----
#pragma unroll
        for (int j = 0; j < 11; ++j) {
            if (!(GUARD && j > r)) {
                const int s = (r - j + 22) % 11;
                va[s]  = fmaf(GW[j], hA, va[s]);
                vb[s]  = fmaf(GW[j], hB, vb[s]);
                vs_[s] = fmaf(GW[j], hS, vs_[s]);
                vp[s]  = fmaf(GW[j], hP, vp[s]);
            }
        }
        // ---- completion: slot (r+1)%11 finished an output row ----
        if (!GUARD || r == 10) {
            const int s = (r + 1) % 11;
            ssim_emit(va[s], vb[s], vs_[s], vp[s], loss_sum);
            va[s] = 0.0f; vb[s] = 0.0f; vs_[s] = 0.0f; vp[s] = 0.0f;
        }
    }
}

// Full per-wave pipeline, specialized on whether the band touches the
// top/bottom image edge (interior bands skip reflect math entirely).
template<bool EDGE>
__device__ __forceinline__ void run_tile(
    const float* __restrict__ A, const float* __restrict__ B,
    int y_start, int c0, int c1, int lane,
    f4 (*__restrict__ buf)[LDS_S4], float& loss_sum)
{
    float va[11], vb[11], vs_[11], vp[11];
#pragma unroll
    for (int j = 0; j < 11; ++j) {
        va[j] = 0.0f; vb[j] = 0.0f; vs_[j] = 0.0f; vp[j] = 0.0f;
    }
    float pa[11], pb[11], pa2[11], pb2[11];

    // prologue: group 0 staged, group 1 prefetched — all within-wave.
    load_group<11, EDGE>(A, B, y_start, 0, c0, c1, lane, pa, pb, pa2, pb2);
    write_group<11>(buf, lane, pa, pb, pa2, pb2);
    load_group<11, EDGE>(A, B, y_start, 11, c0, c1, lane, pa, pb, pa2, pb2);
    process_group<11, true>(buf, lane, va, vb, vs_, vp, loss_sum);

    // main loop: write(g) -> load(g+1) -> process(g). Single buffer:
    // in-order DS per wave orders write(g) before read(g) before write(g+1).
#pragma unroll 1
    for (int g = 1; g <= 11; ++g) {
        write_group<11>(buf, lane, pa, pb, pa2, pb2);   // prefetched group g
        if (g <= 10)
            load_group<11, EDGE>(A, B, y_start, (g + 1) * 11, c0, c1, lane,
                                 pa, pb, pa2, pb2);
        else
            load_group<6, EDGE>(A, B, y_start, 132, c0, c1, lane,
                                pa, pb, pa2, pb2);
        process_group<11, false>(buf, lane, va, vb, vs_, vp, loss_sum);
    }

    // tail: group 12, rows 132..137 (132 % 11 == 0)
    write_group<6>(buf, lane, pa, pb, pa2, pb2);
    process_group<6, false>(buf, lane, va, vb, vs_, vp, loss_sum);
}

__global__ __launch_bounds__(256, 2) void ssim_main(
    const float* __restrict__ inp, const float* __restrict__ tgt,
    float* __restrict__ out)
{
    // Per-wave private single-buffered group storage: 4 waves.
    __shared__ f4 lds[4][11][LDS_S4];   // 53.5 KB
    __shared__ float red[4];

    const int tid  = threadIdx.x;
    const int lane = tid & 63;
    const int w    = tid >> 6;          // wave 0..3
    const int blk  = blockIdx.x;
    // 2048 wave-tiles: img(16) x colstrip(16) x band(8); 4 strips/block
    const int b    = blk >> 5;          // image 0..15
    const int rem  = blk & 31;
    const int ry   = rem >> 2;          // row band 0..7
    const int cs   = (rem & 3) * 4 + w; // column strip 0..15
    const int x0   = cs * WAVE_W;
    const int y0   = ry * TILE_H;

    const float* __restrict__ A = inp + (size_t)b * (H_IMG * (size_t)W_IMG);
    const float* __restrict__ B = tgt + (size_t)b * (H_IMG * (size_t)W_IMG);

    const int c0 = reflect_i(x0 - PADR + lane, W_IMG);
    const int c1 = (lane < 2 * PADR)
                       ? reflect_i(x0 + WAVE_W - PADR + lane, W_IMG) : 0;

    float loss_sum = 0.0f;
    const int y_start = y0 - PADR;  // 138 input rows: 12 groups of 11 + 6

    if (ry == 0 || ry == 7)
        run_tile<true>(A, B, y_start, c0, c1, lane, lds[w], loss_sum);
    else
        run_tile<false>(A, B, y_start, c0, c1, lane, lds[w], loss_sum);

    // ---- reduction: wave shuffle -> LDS across 4 waves -> atomicAdd ----
#pragma unroll
    for (int off = 32; off > 0; off >>= 1)
        loss_sum += __shfl_down(loss_sum, off, 64);
    if (lane == 0) red[w] = loss_sum;
    __syncthreads();   // the only barrier: final 4-wave reduction
    if (tid == 0) {
        const float s = red[0] + red[1] + red[2] + red[3];
        atomicAdd(out, s * (1.0f / ((float)N_IMG * H_IMG * W_IMG)));
    }
}

extern "C" void kernel_launch(void* const* d_in, const int* in_sizes, int n_in,
                              void* d_out, int out_size, void* d_ws, size_t ws_size,
                              hipStream_t stream) {
    const float* inp = (const float*)d_in[0];
    const float* tgt = (const float*)d_in[1];
    float* out = (float*)d_out;

    // d_out is poisoned 0xAA before every launch; zero it for the atomic sum.
    hipMemsetAsync(out, 0, sizeof(float), stream);

    const int grid = N_IMG * 4 * (H_IMG / TILE_H);  // 512 blocks x 4 waves
    ssim_main<<<grid, 256, 0, stream>>>(inp, tgt, out);
}

// Round 9
// 190.965 us; speedup vs baseline: 1.3606x; 1.3606x over previous
//
#include <hip/hip_runtime.h>
#include <math.h>

// SSIM-with-logits fused kernel for MI355X (gfx950). Round 13.
// R12 post-mortem: 4-channel f4 staging spilled (compiler hoists 11
// ds_read_b128 -> ~44 transient quad-aligned VGPRs on top of ring+prefetch)
// AND was issue-neutral by arithmetic: VALU -74 cyc/row, DS +74 cyc/row
// (staged bytes doubled). Lesson: per-pixel issue cost is conserved across
// channel refactors; the ~50% dependency-stall fraction (775 measured vs
// ~380 issue cycles/row at 2 waves/SIMD) is the real target -> need TLP.
// Residency has never been allowed >8 waves/CU by LDS+grid simultaneously.
// R13: R9's proven f2 pipeline (89us, absmax 0.0) with:
//  - SINGLE buffer per wave (R12 validated in-wave DS ordering):
//    LDS 53.5 -> 26.1 KB  (5 blocks/CU fit)
//  - TILE_H 128 -> 64: grid 1024 = 4 blocks/CU; VGPR ~104 allows
//    4 waves/SIMD -> target 16 waves/CU (2x TLP to fill stalls)
//  - deep register prefetch kept (only technique that ever helped)
//  - EDGE-templated bands (R12, free): 14/16 bands skip reflect_i
//  - __launch_bounds__(256,2): proven spill-free MINIMUM (not a cap)

typedef __attribute__((ext_vector_type(2))) float f2;

#define H_IMG 1024
#define W_IMG 1024
#define N_IMG 16
#define WAVE_W 64        // output columns per wave
#define TILE_H 64        // output rows per wave
#define PADR 5
#define LDS_S2 76        // f2 cells per staged row (64 + 10 halo + pad)

// Normalized 1D Gaussian, WS=11, sigma=1.5 (absmax 0.0 in R1-R12)
constexpr float GW[11] = {
    0.00102838f, 0.00759877f, 0.03600077f, 0.10936069f, 0.21300553f,
    0.26601172f,
    0.21300553f, 0.10936069f, 0.03600077f, 0.00759877f, 0.00102838f};

__device__ __forceinline__ int reflect_i(int i, int n) {
    i = (i < 0) ? -i : i;
    i = (i >= n) ? (2 * n - 2 - i) : i;
    return i;
}

__device__ __forceinline__ float fast_sigmoid(float x) {
    return __builtin_amdgcn_rcpf(1.0f + __expf(-x));
}

// mu = (mu1, mu2); sx = (F(a^2)+F(b^2), F(ab))  [sigma-sum trick, R8-proven]
__device__ __forceinline__ void ssim_emit(
    f2 mu, f2 sx, float& loss_sum)
{
    const float mu1 = mu.x, mu2 = mu.y;
    const float mu1s = mu1 * mu1;
    const float mu2s = mu2 * mu2;
    const float mu12 = mu1 * mu2;
    const float ssum = sx.x - mu1s - mu2s;   // sigma1^2 + sigma2^2
    const float s12  = sx.y - mu12;
    const float C1 = 1e-4f, C2 = 9e-4f;
    const float num = (2.0f * mu12 + C1) * (2.0f * s12 + C2);
    const float den = (mu1s + mu2s + C1) * (ssum + C2);
    float l = 1.0f - num * __builtin_amdgcn_rcpf(den);
    l = fminf(fmaxf(l, 0.0f), 1.0f) * 0.5f;
    loss_sum += l;
}

// Issue global loads for NR rows of group at base gb into prefetch regs.
// EDGE=false (interior bands): row index always in range, no reflect.
template<int NR, bool EDGE>
__device__ __forceinline__ void load_group(
    const float* __restrict__ A, const float* __restrict__ B,
    int y_start, int gb, int c0, int c1, int lane,
    float (&pa)[11], float (&pb)[11], float (&pa2)[11], float (&pb2)[11])
{
#pragma unroll
    for (int r = 0; r < NR; ++r) {
        const int yr = y_start + gb + r;
        const int yy = EDGE ? reflect_i(yr, H_IMG) : yr;
        const size_t ro = (size_t)yy << 10;   // *W_IMG
        pa[r] = A[ro + c0];
        pb[r] = B[ro + c0];
        if (lane < 2 * PADR) {
            pa2[r] = A[ro + c1];
            pb2[r] = B[ro + c1];
        }
    }
}

// Sigmoid + write NR prefetched rows into this wave's LDS buffer.
template<int NR>
__device__ __forceinline__ void write_group(
    f2 (*__restrict__ buf)[LDS_S2], int lane,
    const float (&pa)[11], const float (&pb)[11],
    const float (&pa2)[11], const float (&pb2)[11])
{
#pragma unroll
    for (int r = 0; r < NR; ++r) {
        buf[r][lane] = (f2){fast_sigmoid(pa[r]), pb[r]};
        if (lane < 2 * PADR)
            buf[r][WAVE_W + lane] = (f2){fast_sigmoid(pa2[r]), pb2[r]};
    }
}

// Process NR staged rows from this wave's buffer. Group base == 0 mod 11
// so mod-11 slot indices fold to compile-time constants (validated R2-R12).
// GUARD: first group (edge); invalid taps skipped, only r==10 completes.
// Single buffer, no barrier: DS ops are in-order within a wave, so this
// group's ds_reads complete before the next group's ds_writes (R12-proven).
template<int NR, bool GUARD>
__device__ __forceinline__ void process_group(
    const f2 (*__restrict__ buf)[LDS_S2], int lane,
    f2 (&vAB)[11], f2 (&vSX)[11], float& loss_sum)
{
#pragma unroll
    for (int r = 0; r < NR; ++r) {
        // ---- horizontal 11-tap, packed (a,b)/(aa,bb) + scalar ab ----
        f2 hAB = (f2)(0.0f), hSQ = (f2)(0.0f);
        float hab = 0.0f;
#pragma unroll
        for (int k = 0; k < 11; ++k) {
            const f2 v   = buf[r][lane + k];
            const f2 wa2 = ((f2)(GW[k])) * v;         // (GW*a, GW*b)
            hAB += wa2;
            hSQ  = __builtin_elementwise_fma(wa2, v, hSQ);
            hab  = fmaf(wa2.x, v.y, hab);
        }
        // collapse (aa,bb) -> aa+bb; pair with ab
        const f2 hSX = (f2){hSQ.x + hSQ.y, hab};
        // ---- vertical scatter into mod-11 slots ----
#pragma unroll
        for (int j = 0; j < 11; ++j) {
            if (!(GUARD && j > r)) {
                const int s = (r - j + 22) % 11;
                const f2 w2 = (f2)(GW[j]);
                vAB[s] = __builtin_elementwise_fma(w2, hAB, vAB[s]);
                vSX[s] = __builtin_elementwise_fma(w2, hSX, vSX[s]);
            }
        }
        // ---- completion: slot (r+1)%11 finished an output row ----
        if (!GUARD || r == 10) {
            const int s = (r + 1) % 11;
            ssim_emit(vAB[s], vSX[s], loss_sum);
            vAB[s] = (f2)(0.0f); vSX[s] = (f2)(0.0f);
        }
    }
}

// Full per-wave pipeline for a 64x64 tile (74 staged rows = 6x11 + 8).
template<bool EDGE>
__device__ __forceinline__ void run_tile(
    const float* __restrict__ A, const float* __restrict__ B,
    int y_start, int c0, int c1, int lane,
    f2 (*__restrict__ buf)[LDS_S2], float& loss_sum)
{
    f2 vAB[11], vSX[11];
#pragma unroll
    for (int j = 0; j < 11; ++j) {
        vAB[j] = (f2)(0.0f); vSX[j] = (f2)(0.0f);
    }
    float pa[11], pb[11], pa2[11], pb2[11];

    // prologue: group 0 staged, group 1 prefetched — all within-wave.
    load_group<11, EDGE>(A, B, y_start, 0, c0, c1, lane, pa, pb, pa2, pb2);
    write_group<11>(buf, lane, pa, pb, pa2, pb2);
    load_group<11, EDGE>(A, B, y_start, 11, c0, c1, lane, pa, pb, pa2, pb2);
    process_group<11, true>(buf, lane, vAB, vSX, loss_sum);

    // main loop: write(g) -> load(g+1) -> process(g). Single buffer:
    // in-order DS per wave orders read(g) before write(g+1).
#pragma unroll 1
    for (int g = 1; g <= 5; ++g) {
        write_group<11>(buf, lane, pa, pb, pa2, pb2);   // prefetched group g
        if (g <= 4)
            load_group<11, EDGE>(A, B, y_start, (g + 1) * 11, c0, c1, lane,
                                 pa, pb, pa2, pb2);
        else
            load_group<8, EDGE>(A, B, y_start, 66, c0, c1, lane,
                                pa, pb, pa2, pb2);
        process_group<11, false>(buf, lane, vAB, vSX, loss_sum);
    }

    // tail: group 6, rows 66..73 (66 % 11 == 0)
    write_group<8>(buf, lane, pa, pb, pa2, pb2);
    process_group<8, false>(buf, lane, vAB, vSX, loss_sum);
}

__global__ __launch_bounds__(256, 2) void ssim_main(
    const float* __restrict__ inp, const float* __restrict__ tgt,
    float* __restrict__ out)
{
    // Per-wave private SINGLE-buffered group storage: 4 waves, 26.1 KB.
    __shared__ f2 lds[4][11][LDS_S2];
    __shared__ float red[4];

    const int tid  = threadIdx.x;
    const int lane = tid & 63;
    const int w    = tid >> 6;          // wave 0..3
    const int blk  = blockIdx.x;
    // 4096 wave-tiles: img(16) x colstrip(16) x band(16); 4 strips/block
    const int b    = blk >> 6;          // image 0..15 (64 blocks/image)
    const int rem  = blk & 63;
    const int ry   = rem >> 2;          // row band 0..15
    const int cs   = (rem & 3) * 4 + w; // column strip 0..15
    const int x0   = cs * WAVE_W;
    const int y0   = ry * TILE_H;

    const float* __restrict__ A = inp + (size_t)b * (H_IMG * (size_t)W_IMG);
    const float* __restrict__ B = tgt + (size_t)b * (H_IMG * (size_t)W_IMG);

    const int c0 = reflect_i(x0 - PADR + lane, W_IMG);
    const int c1 = (lane < 2 * PADR)
                       ? reflect_i(x0 + WAVE_W - PADR + lane, W_IMG) : 0;

    float loss_sum = 0.0f;
    const int y_start = y0 - PADR;  // 74 input rows: 6 groups of 11 + 8

    if (ry == 0 || ry == 15)
        run_tile<true>(A, B, y_start, c0, c1, lane, lds[w], loss_sum);
    else
        run_tile<false>(A, B, y_start, c0, c1, lane, lds[w], loss_sum);

    // ---- reduction: wave shuffle -> LDS across 4 waves -> atomicAdd ----
#pragma unroll
    for (int off = 32; off > 0; off >>= 1)
        loss_sum += __shfl_down(loss_sum, off, 64);
    if (lane == 0) red[w] = loss_sum;
    __syncthreads();   // the only barrier: final 4-wave reduction
    if (tid == 0) {
        const float s = red[0] + red[1] + red[2] + red[3];
        atomicAdd(out, s * (1.0f / ((float)N_IMG * H_IMG * W_IMG)));
    }
}

extern "C" void kernel_launch(void* const* d_in, const int* in_sizes, int n_in,
                              void* d_out, int out_size, void* d_ws, size_t ws_size,
                              hipStream_t stream) {
    const float* inp = (const float*)d_in[0];
    const float* tgt = (const float*)d_in[1];
    float* out = (float*)d_out;

    // d_out is poisoned 0xAA before every launch; zero it for the atomic sum.
    hipMemsetAsync(out, 0, sizeof(float), stream);

    const int grid = N_IMG * 4 * (H_IMG / TILE_H);  // 1024 blocks, 4/CU
    ssim_main<<<grid, 256, 0, stream>>>(inp, tgt, out);
}

// Round 10
// 185.037 us; speedup vs baseline: 1.4042x; 1.0320x over previous
//
#include <hip/hip_runtime.h>
#include <math.h>

// SSIM-with-logits fused kernel for MI355X (gfx950). Round 14.
// R13 post-mortem: VGPR 116 / LDS 27KB / grid 1024 / no spill -> occupancy
// STILL 19%, 96us = 89us x halo tax. R5-R13 varied VGPR/LDS/grid/block/
// barriers; perf NEVER responded to residency. The 89us floor is per-wave:
// ~154 VALU/row (~308 cyc issue) vs measured ~775 cyc/row -> ~40% per-wave
// stall, consistent with the 11 ds_read_b64 taps being issued and consumed
// in the SAME row body (ds_read latency ~120 cyc, 2 waves/SIMD can't cover).
// R14: cross-row tap prefetch. In process_group, row r+1's 11 taps are
// read into registers BEFORE row r's ~280 cycles of h-pass+vertical math;
// ping-pong arrays selected by (r&1), folded by the full unroll (no
// runtime indexing -> no scratch). One cold row per 11 (group boundary).
// Base kept: R9 structure (TILE_H=128, no barriers, 44-reg global
// prefetch, sigma-sum ring) + R13 single-buffer LDS (26.75KB) + EDGE.
// Register math: ring 44 + gprefetch 44 + taps 44 + temps ~= 155 live;
// (256,2) next tier budget ~170 (3 waves/SIMD) -> no spill expected.
// Kill-switch: WRITE_SIZE > 1MB => ping-pong spilled => revert.

typedef __attribute__((ext_vector_type(2))) float f2;

#define H_IMG 1024
#define W_IMG 1024
#define N_IMG 16
#define WAVE_W 64        // output columns per wave
#define TILE_H 128       // output rows per wave
#define PADR 5
#define LDS_S2 76        // f2 cells per staged row (64 + 10 halo + pad)

// Normalized 1D Gaussian, WS=11, sigma=1.5 (absmax 0.0 in R1-R13)
constexpr float GW[11] = {
    0.00102838f, 0.00759877f, 0.03600077f, 0.10936069f, 0.21300553f,
    0.26601172f,
    0.21300553f, 0.10936069f, 0.03600077f, 0.00759877f, 0.00102838f};

__device__ __forceinline__ int reflect_i(int i, int n) {
    i = (i < 0) ? -i : i;
    i = (i >= n) ? (2 * n - 2 - i) : i;
    return i;
}

__device__ __forceinline__ float fast_sigmoid(float x) {
    return __builtin_amdgcn_rcpf(1.0f + __expf(-x));
}

// mu = (mu1, mu2); sx = (F(a^2)+F(b^2), F(ab))  [sigma-sum trick, R8-proven]
__device__ __forceinline__ void ssim_emit(
    f2 mu, f2 sx, float& loss_sum)
{
    const float mu1 = mu.x, mu2 = mu.y;
    const float mu1s = mu1 * mu1;
    const float mu2s = mu2 * mu2;
    const float mu12 = mu1 * mu2;
    const float ssum = sx.x - mu1s - mu2s;   // sigma1^2 + sigma2^2
    const float s12  = sx.y - mu12;
    const float C1 = 1e-4f, C2 = 9e-4f;
    const float num = (2.0f * mu12 + C1) * (2.0f * s12 + C2);
    const float den = (mu1s + mu2s + C1) * (ssum + C2);
    float l = 1.0f - num * __builtin_amdgcn_rcpf(den);
    l = fminf(fmaxf(l, 0.0f), 1.0f) * 0.5f;
    loss_sum += l;
}

// Issue global loads for NR rows of group at base gb into prefetch regs.
// EDGE=false (interior bands): row index always in range, no reflect.
template<int NR, bool EDGE>
__device__ __forceinline__ void load_group(
    const float* __restrict__ A, const float* __restrict__ B,
    int y_start, int gb, int c0, int c1, int lane,
    float (&pa)[11], float (&pb)[11], float (&pa2)[11], float (&pb2)[11])
{
#pragma unroll
    for (int r = 0; r < NR; ++r) {
        const int yr = y_start + gb + r;
        const int yy = EDGE ? reflect_i(yr, H_IMG) : yr;
        const size_t ro = (size_t)yy << 10;   // *W_IMG
        pa[r] = A[ro + c0];
        pb[r] = B[ro + c0];
        if (lane < 2 * PADR) {
            pa2[r] = A[ro + c1];
            pb2[r] = B[ro + c1];
        }
    }
}

// Sigmoid + write NR prefetched rows into this wave's LDS buffer.
template<int NR>
__device__ __forceinline__ void write_group(
    f2 (*__restrict__ buf)[LDS_S2], int lane,
    const float (&pa)[11], const float (&pb)[11],
    const float (&pa2)[11], const float (&pb2)[11])
{
#pragma unroll
    for (int r = 0; r < NR; ++r) {
        buf[r][lane] = (f2){fast_sigmoid(pa[r]), pb[r]};
        if (lane < 2 * PADR)
            buf[r][WAVE_W + lane] = (f2){fast_sigmoid(pa2[r]), pb2[r]};
    }
}

// Process NR staged rows. Group base == 0 mod 11 -> slot indices fold to
// compile-time constants (validated R2-R13). GUARD: first group (edge).
// Cross-row tap prefetch: row r+1's taps are loaded into the ping-pong
// register array while row r's ~280 cycles of math run -> LDS latency
// hidden within the wave. cur/nxt selection folds at compile time (full
// unroll makes r a literal; no runtime-indexed arrays -> no scratch).
template<int NR, bool GUARD>
__device__ __forceinline__ void process_group(
    const f2 (*__restrict__ buf)[LDS_S2], int lane,
    f2 (&vAB)[11], f2 (&vSX)[11], float& loss_sum)
{
    f2 tA[11], tB[11];
#pragma unroll
    for (int k = 0; k < 11; ++k) tA[k] = buf[0][lane + k];

#pragma unroll
    for (int r = 0; r < NR; ++r) {
        f2 (&cur)[11] = (r & 1) ? tB : tA;   // r literal after unroll
        f2 (&nxt)[11] = (r & 1) ? tA : tB;
        // issue next row's tap reads first; consumed ~140 instrs later
        if (r + 1 < NR) {
#pragma unroll
            for (int k = 0; k < 11; ++k) nxt[k] = buf[r + 1][lane + k];
        }
        // ---- horizontal 11-tap from registers ----
        f2 hAB = (f2)(0.0f), hSQ = (f2)(0.0f);
        float hab = 0.0f;
#pragma unroll
        for (int k = 0; k < 11; ++k) {
            const f2 v   = cur[k];
            const f2 wa2 = ((f2)(GW[k])) * v;         // (GW*a, GW*b)
            hAB += wa2;
            hSQ  = __builtin_elementwise_fma(wa2, v, hSQ);
            hab  = fmaf(wa2.x, v.y, hab);
        }
        const f2 hSX = (f2){hSQ.x + hSQ.y, hab};
        // ---- vertical scatter into mod-11 slots ----
#pragma unroll
        for (int j = 0; j < 11; ++j) {
            if (!(GUARD && j > r)) {
                const int s = (r - j + 22) % 11;
                const f2 w2 = (f2)(GW[j]);
                vAB[s] = __builtin_elementwise_fma(w2, hAB, vAB[s]);
                vSX[s] = __builtin_elementwise_fma(w2, hSX, vSX[s]);
            }
        }
        // ---- completion: slot (r+1)%11 finished an output row ----
        if (!GUARD || r == 10) {
            const int s = (r + 1) % 11;
            ssim_emit(vAB[s], vSX[s], loss_sum);
            vAB[s] = (f2)(0.0f); vSX[s] = (f2)(0.0f);
        }
    }
}

// Full per-wave pipeline for a 64x128 tile (138 staged rows = 12x11 + 6).
template<bool EDGE>
__device__ __forceinline__ void run_tile(
    const float* __restrict__ A, const float* __restrict__ B,
    int y_start, int c0, int c1, int lane,
    f2 (*__restrict__ buf)[LDS_S2], float& loss_sum)
{
    f2 vAB[11], vSX[11];
#pragma unroll
    for (int j = 0; j < 11; ++j) {
        vAB[j] = (f2)(0.0f); vSX[j] = (f2)(0.0f);
    }
    float pa[11], pb[11], pa2[11], pb2[11];

    // prologue: group 0 staged, group 1 prefetched — all within-wave.
    load_group<11, EDGE>(A, B, y_start, 0, c0, c1, lane, pa, pb, pa2, pb2);
    write_group<11>(buf, lane, pa, pb, pa2, pb2);
    load_group<11, EDGE>(A, B, y_start, 11, c0, c1, lane, pa, pb, pa2, pb2);
    process_group<11, true>(buf, lane, vAB, vSX, loss_sum);

    // main loop: write(g) -> load(g+1) -> process(g). Single buffer:
    // in-order DS per wave orders read(g) before write(g+1) (R12/R13).
#pragma unroll 1
    for (int g = 1; g <= 11; ++g) {
        write_group<11>(buf, lane, pa, pb, pa2, pb2);   // prefetched group g
        if (g <= 10)
            load_group<11, EDGE>(A, B, y_start, (g + 1) * 11, c0, c1, lane,
                                 pa, pb, pa2, pb2);
        else
            load_group<6, EDGE>(A, B, y_start, 132, c0, c1, lane,
                                pa, pb, pa2, pb2);
        process_group<11, false>(buf, lane, vAB, vSX, loss_sum);
    }

    // tail: group 12, rows 132..137 (132 % 11 == 0)
    write_group<6>(buf, lane, pa, pb, pa2, pb2);
    process_group<6, false>(buf, lane, vAB, vSX, loss_sum);
}

__global__ __launch_bounds__(256, 2) void ssim_main(
    const float* __restrict__ inp, const float* __restrict__ tgt,
    float* __restrict__ out)
{
    // Per-wave private SINGLE-buffered group storage: 4 waves, 26.75 KB.
    __shared__ f2 lds[4][11][LDS_S2];
    __shared__ float red[4];

    const int tid  = threadIdx.x;
    const int lane = tid & 63;
    const int w    = tid >> 6;          // wave 0..3
    const int blk  = blockIdx.x;
    // 2048 wave-tiles: img(16) x colstrip(16) x band(8); 4 strips/block
    const int b    = blk >> 5;          // image 0..15
    const int rem  = blk & 31;
    const int ry   = rem >> 2;          // row band 0..7
    const int cs   = (rem & 3) * 4 + w; // column strip 0..15
    const int x0   = cs * WAVE_W;
    const int y0   = ry * TILE_H;

    const float* __restrict__ A = inp + (size_t)b * (H_IMG * (size_t)W_IMG);
    const float* __restrict__ B = tgt + (size_t)b * (H_IMG * (size_t)W_IMG);

    const int c0 = reflect_i(x0 - PADR + lane, W_IMG);
    const int c1 = (lane < 2 * PADR)
                       ? reflect_i(x0 + WAVE_W - PADR + lane, W_IMG) : 0;

    float loss_sum = 0.0f;
    const int y_start = y0 - PADR;  // 138 input rows: 12 groups of 11 + 6

    if (ry == 0 || ry == 7)
        run_tile<true>(A, B, y_start, c0, c1, lane, lds[w], loss_sum);
    else
        run_tile<false>(A, B, y_start, c0, c1, lane, lds[w], loss_sum);

    // ---- reduction: wave shuffle -> LDS across 4 waves -> atomicAdd ----
#pragma unroll
    for (int off = 32; off > 0; off >>= 1)
        loss_sum += __shfl_down(loss_sum, off, 64);
    if (lane == 0) red[w] = loss_sum;
    __syncthreads();   // the only barrier: final 4-wave reduction
    if (tid == 0) {
        const float s = red[0] + red[1] + red[2] + red[3];
        atomicAdd(out, s * (1.0f / ((float)N_IMG * H_IMG * W_IMG)));
    }
}

extern "C" void kernel_launch(void* const* d_in, const int* in_sizes, int n_in,
                              void* d_out, int out_size, void* d_ws, size_t ws_size,
                              hipStream_t stream) {
    const float* inp = (const float*)d_in[0];
    const float* tgt = (const float*)d_in[1];
    float* out = (float*)d_out;

    // d_out is poisoned 0xAA before every launch; zero it for the atomic sum.
    hipMemsetAsync(out, 0, sizeof(float), stream);

    const int grid = N_IMG * 4 * (H_IMG / TILE_H);  // 512 blocks x 4 waves
    ssim_main<<<grid, 256, 0, stream>>>(inp, tgt, out);
}